// Round 1
// baseline (341.057 us; speedup 1.0000x reference)
//
#include <hip/hip_runtime.h>

#define IN_F 128
#define OUT_F 32
#define WT_LD 132   // 128 + 4 pad: keeps 16B alignment, spreads Wt column reads
                    // across all 32 banks exactly 4x (= b128 BW minimum, no conflict)

typedef float vf4 __attribute__((ext_vector_type(4)));

// ---------------------------------------------------------------------------
// Kernel 1: z = x @ W + b   (100000 x 128) * (128 x 32)
// Block: 256 threads, 64 rows/block.
// LDS: x tile 64*128*4 = 32 KB, Wt (transposed, padded) 32*132*4 = 16.9 KB
//      -> 49.8 KB -> 3 blocks/CU (12 waves).
// Inner loop is float4-vectorized over k: per 4-k step a thread issues
// 8x ds_read_b128 (x rows, broadcast within 32-lane col group) +
// 1x ds_read_b128 (Wt column) + 32 FMA  => VALU-bound (was 9 scalar
// ds_read_b32 per k = LDS-issue-bound, ~3x over the FMA floor).
// ---------------------------------------------------------------------------
__global__ __launch_bounds__(256) void zgemm_kernel(
    const float* __restrict__ x, const float* __restrict__ W,
    const float* __restrict__ b, float* __restrict__ z, int n_nodes)
{
    __shared__ float xs[64 * IN_F];        // 32 KB
    __shared__ float Wt[OUT_F * WT_LD];    // 16.9 KB, Wt[col][k]
    __shared__ float bs[OUT_F];

    const int t = threadIdx.x;
    const int row0 = blockIdx.x * 64;
    const int rows = min(64, n_nodes - row0);

    // Stage W transposed: coalesced float4 global reads, b32 LDS scatter
    // (one-time cost, ~4-way write aliasing is negligible for 16 writes).
    {
        const vf4* Wv = (const vf4*)W;
        #pragma unroll
        for (int i = 0; i < 4; ++i) {
            const int idx4 = t + i * 256;        // 0..1023
            const vf4 w = Wv[idx4];
            const int k  = idx4 >> 3;            // 0..127
            const int c0 = (idx4 & 7) << 2;      // 0,4,...,28
            Wt[(c0 + 0) * WT_LD + k] = w.x;
            Wt[(c0 + 1) * WT_LD + k] = w.y;
            Wt[(c0 + 2) * WT_LD + k] = w.z;
            Wt[(c0 + 3) * WT_LD + k] = w.w;
        }
        if (t < OUT_F) bs[t] = b[t];
    }
    // Stage x tile — coalesced, nontemporal (x is read exactly once; keep it
    // out of L2 so W/z stay resident).
    {
        const vf4* xv = (const vf4*)(x + (size_t)row0 * IN_F);
        vf4* xsv = (vf4*)xs;
        const int nv = rows * (IN_F / 4);
        for (int i = t; i < nv; i += 256)
            xsv[i] = __builtin_nontemporal_load(xv + i);
    }
    __syncthreads();

    const int col = t & 31;
    const int rg  = t >> 5;   // 0..7

    float acc[8];
    #pragma unroll
    for (int i = 0; i < 8; ++i) acc[i] = 0.f;

    const vf4* Wc = (const vf4*)(Wt + col * WT_LD);  // 528 B stride, 16B-aligned
    #pragma unroll 4
    for (int k4 = 0; k4 < IN_F / 4; ++k4) {
        const vf4 w4 = Wc[k4];
        #pragma unroll
        for (int i = 0; i < 8; ++i) {
            const vf4 x4 = *(const vf4*)(xs + (rg + i * 8) * IN_F + (k4 << 2));
            acc[i] += x4.x * w4.x;
            acc[i] += x4.y * w4.y;
            acc[i] += x4.z * w4.z;
            acc[i] += x4.w * w4.w;
        }
    }

    const float bb = bs[col];
    #pragma unroll
    for (int i = 0; i < 8; ++i) {
        const int r = rg + i * 8;
        if (r < rows)
            z[(size_t)(row0 + r) * OUT_F + col] = acc[i] + bb;   // coalesced 128B/rg
    }
}

// ---------------------------------------------------------------------------
// Kernel 2: out[e][:] = vals[e] * (z[rows[e]][:] + z[cols[e]][:])
// 8 lanes per edge, float4/lane -> wave writes 1 KB contiguous.
// z (12.8 MB) is the only data we WANT cached: index/val streams use
// nontemporal loads and the out stream uses nontemporal stores so the
// 224 MB of streaming traffic doesn't evict z from the per-XCD L2s.
// Grid-stride at 4096 blocks instead of 50k tiny blocks.
// ---------------------------------------------------------------------------
__global__ __launch_bounds__(256) void edge_kernel(
    const int* __restrict__ erows, const int* __restrict__ ecols,
    const float* __restrict__ evals, const float* __restrict__ z,
    float* __restrict__ out, int n_edges)
{
    const size_t total  = (size_t)n_edges * 8;
    const size_t stride = (size_t)gridDim.x * 256;
    for (size_t g = (size_t)blockIdx.x * 256 + threadIdx.x; g < total; g += stride) {
        const size_t e = g >> 3;
        const int joff = (int)(g & 7) << 2;   // 0,4,...,28

        const int   r = __builtin_nontemporal_load(erows + e);
        const int   c = __builtin_nontemporal_load(ecols + e);
        const float w = __builtin_nontemporal_load(evals + e);

        const vf4 zr = *(const vf4*)(z + (size_t)r * OUT_F + joff);
        const vf4 zc = *(const vf4*)(z + (size_t)c * OUT_F + joff);

        vf4 o;
        o.x = w * (zr.x + zc.x);
        o.y = w * (zr.y + zc.y);
        o.z = w * (zr.z + zc.z);
        o.w = w * (zr.w + zc.w);

        __builtin_nontemporal_store(o, (vf4*)(out + e * OUT_F + joff));
    }
}

extern "C" void kernel_launch(void* const* d_in, const int* in_sizes, int n_in,
                              void* d_out, int out_size, void* d_ws, size_t ws_size,
                              hipStream_t stream)
{
    const float* x  = (const float*)d_in[0];   // (100000, 128)
    const float* W  = (const float*)d_in[1];   // (128, 32)
    const float* b  = (const float*)d_in[2];   // (32,)
    const int* erow = (const int*)d_in[3];     // (E,) int32
    const int* ecol = (const int*)d_in[4];     // (E,) int32
    const float* ev = (const float*)d_in[5];   // (E,)

    const int n_nodes = in_sizes[0] / IN_F;
    const int n_edges = in_sizes[3];

    float* z   = (float*)d_ws;                 // n_nodes*32*4 = 12.8 MB scratch
    float* out = (float*)d_out;                // (E, 32)

    const int gemm_blocks = (n_nodes + 63) / 64;
    zgemm_kernel<<<gemm_blocks, 256, 0, stream>>>(x, W, b, z, n_nodes);

    const size_t total_thr = (size_t)n_edges * 8;
    int edge_blocks = (int)((total_thr + 255) / 256);
    if (edge_blocks > 4096) edge_blocks = 4096;
    edge_kernel<<<edge_blocks, 256, 0, stream>>>(erow, ecol, ev, z, out, n_edges);
}

// Round 3
// 319.936 us; speedup vs baseline: 1.0660x; 1.0660x over previous
//
#include <hip/hip_runtime.h>

#define IN_F 128
#define OUT_F 32
#define XS_LD 132   // 128 + 4 pad. 132 dwords = 528 B = 33*16 B: keeps vf4
                    // alignment, and makes row r's k-window start at bank
                    // (4r + 4k4) mod 32 -> 8 wave-rows tile all 32 banks
                    // exactly once (perfect broadcast, conflict-free b128).

typedef float vf4 __attribute__((ext_vector_type(4)));

// ---------------------------------------------------------------------------
// Kernel 1: z = x @ W + b   (100000 x 128) * (128 x 32)
// Block: 256 threads, 64 rows/block.
// Thread (cg = t&7, rgg = t>>3): cols 4cg..4cg+3, rows {rgg, rgg+32}.
// Per k4-step: 2 x-reads (b128 over k, padded stride -> conflict-free
// broadcast) + 4 W-reads (b128 over cols from row-major W -> 8 cg windows
// tile 32 banks, broadcast x8, conflict-free) + 32 FMAs.
// => LDS issue ~36 cyc < VALU issue 64 cyc per wave: VALU-bound at the
// ~5 us FMA floor (was 9 reads/32 FMAs with a 4-way-conflicted Wt read).
// LDS: 33.8 KB x + 16 KB W -> 50.3 KB -> 3 blocks/CU.
// ---------------------------------------------------------------------------
__global__ __launch_bounds__(256) void zgemm_kernel(
    const float* __restrict__ x, const float* __restrict__ W,
    const float* __restrict__ b, float* __restrict__ z, int n_nodes)
{
    __shared__ float xs[64 * XS_LD];     // 33.8 KB (padded)
    __shared__ float Ws[IN_F * OUT_F];   // 16 KB, row-major as in global
    __shared__ float bs[OUT_F];

    const int t = threadIdx.x;
    const int row0 = blockIdx.x * 64;
    const int rows = min(64, n_nodes - row0);

    // Stage W (1024 vf4, 4 per thread) — coalesced, layout unchanged.
    {
        const vf4* Wv = (const vf4*)W;
        vf4* Wsv = (vf4*)Ws;
        #pragma unroll
        for (int i = 0; i < 4; ++i)
            Wsv[t + i * 256] = Wv[t + i * 256];
        if (t < OUT_F) bs[t] = b[t];
    }
    // Stage x tile — coalesced global vf4 reads, padded LDS scatter
    // (row*132 dwords is 16B-aligned since 132*4 = 33*16).
    {
        const vf4* xv = (const vf4*)(x + (size_t)row0 * IN_F);
        const int nv = rows * (IN_F / 4);
        for (int i = t; i < nv; i += 256) {
            const int row = i >> 5;
            const int kk  = i & 31;
            *(vf4*)(xs + row * XS_LD + (kk << 2)) = xv[i];
        }
    }
    __syncthreads();

    const int cg  = t & 7;     // col group: cols 4cg..4cg+3
    const int rgg = t >> 3;    // row group: rows rgg, rgg+32
    const int c0  = cg << 2;

    vf4 acc0 = {0.f, 0.f, 0.f, 0.f};
    vf4 acc1 = {0.f, 0.f, 0.f, 0.f};

    #pragma unroll 4
    for (int k4 = 0; k4 < IN_F / 4; ++k4) {
        const vf4 xa = *(const vf4*)(xs + rgg * XS_LD + (k4 << 2));
        const vf4 xb = *(const vf4*)(xs + (rgg + 32) * XS_LD + (k4 << 2));
        const vf4 w0 = *(const vf4*)(Ws + ((k4 << 2) + 0) * OUT_F + c0);
        const vf4 w1 = *(const vf4*)(Ws + ((k4 << 2) + 1) * OUT_F + c0);
        const vf4 w2 = *(const vf4*)(Ws + ((k4 << 2) + 2) * OUT_F + c0);
        const vf4 w3 = *(const vf4*)(Ws + ((k4 << 2) + 3) * OUT_F + c0);

        acc0 += xa.x * w0;  acc0 += xa.y * w1;
        acc0 += xa.z * w2;  acc0 += xa.w * w3;
        acc1 += xb.x * w0;  acc1 += xb.y * w1;
        acc1 += xb.z * w2;  acc1 += xb.w * w3;
    }

    const vf4 bb = *(const vf4*)(bs + c0);

    if (rgg < rows)
        *(vf4*)(z + (size_t)(row0 + rgg) * OUT_F + c0) = acc0 + bb;
    if (rgg + 32 < rows)
        *(vf4*)(z + (size_t)(row0 + rgg + 32) * OUT_F + c0) = acc1 + bb;
}

// ---------------------------------------------------------------------------
// Kernel 2: out[e][:] = vals[e] * (z[rows[e]][:] + z[cols[e]][:])
// EXACT round-0 version (best measured config).
// 8 lanes per edge, float4 per lane -> one wave covers 8 consecutive edges,
// writing 1024 contiguous bytes (perfectly coalesced).
// ---------------------------------------------------------------------------
__global__ __launch_bounds__(256) void edge_kernel(
    const int* __restrict__ erows, const int* __restrict__ ecols,
    const float* __restrict__ evals, const float* __restrict__ z,
    float* __restrict__ out, int n_edges)
{
    const size_t g = (size_t)blockIdx.x * 256 + threadIdx.x;
    const size_t e = g >> 3;
    if (e >= (size_t)n_edges) return;
    const int joff = (int)(g & 7) << 2;   // 0,4,8,...,28

    const int r = erows[e];
    const int c = ecols[e];
    const float w = evals[e];

    const float4 zr = *(const float4*)(z + (size_t)r * OUT_F + joff);
    const float4 zc = *(const float4*)(z + (size_t)c * OUT_F + joff);

    float4 o;
    o.x = w * (zr.x + zc.x);
    o.y = w * (zr.y + zc.y);
    o.z = w * (zr.z + zc.z);
    o.w = w * (zr.w + zc.w);

    *(float4*)(out + e * OUT_F + joff) = o;
}

extern "C" void kernel_launch(void* const* d_in, const int* in_sizes, int n_in,
                              void* d_out, int out_size, void* d_ws, size_t ws_size,
                              hipStream_t stream)
{
    const float* x  = (const float*)d_in[0];   // (100000, 128)
    const float* W  = (const float*)d_in[1];   // (128, 32)
    const float* b  = (const float*)d_in[2];   // (32,)
    const int* erow = (const int*)d_in[3];     // (E,) int32
    const int* ecol = (const int*)d_in[4];     // (E,) int32
    const float* ev = (const float*)d_in[5];   // (E,)

    const int n_nodes = in_sizes[0] / IN_F;
    const int n_edges = in_sizes[3];

    float* z   = (float*)d_ws;                 // n_nodes*32*4 = 12.8 MB scratch
    float* out = (float*)d_out;                // (E, 32)

    const int gemm_blocks = (n_nodes + 63) / 64;
    zgemm_kernel<<<gemm_blocks, 256, 0, stream>>>(x, W, b, z, n_nodes);

    const size_t total_thr = (size_t)n_edges * 8;
    const int edge_blocks = (int)((total_thr + 255) / 256);
    edge_kernel<<<edge_blocks, 256, 0, stream>>>(erow, ecol, ev, z, out, n_edges);
}

// Round 4
// 309.648 us; speedup vs baseline: 1.1014x; 1.0332x over previous
//
#include <hip/hip_runtime.h>

#define IN_F 128
#define OUT_F 32
#define XS_LD 132   // 128 + 4 pad. 132 dwords = 528 B = 33*16 B: keeps vf4
                    // alignment, and makes row r's k-window start at bank
                    // (4r + 4k4) mod 32 -> 8 wave-rows tile all 32 banks
                    // exactly once (perfect broadcast, conflict-free b128).

typedef float vf4 __attribute__((ext_vector_type(4)));

// ---------------------------------------------------------------------------
// Kernel 1: z = x @ W + b   (100000 x 128) * (128 x 32)
// UNCHANGED from round 3 (best measured; ~15-40 us, near its floor).
// ---------------------------------------------------------------------------
__global__ __launch_bounds__(256) void zgemm_kernel(
    const float* __restrict__ x, const float* __restrict__ W,
    const float* __restrict__ b, float* __restrict__ z, int n_nodes)
{
    __shared__ float xs[64 * XS_LD];     // 33.8 KB (padded)
    __shared__ float Ws[IN_F * OUT_F];   // 16 KB, row-major as in global
    __shared__ float bs[OUT_F];

    const int t = threadIdx.x;
    const int row0 = blockIdx.x * 64;
    const int rows = min(64, n_nodes - row0);

    // Stage W (1024 vf4, 4 per thread) — coalesced, layout unchanged.
    {
        const vf4* Wv = (const vf4*)W;
        vf4* Wsv = (vf4*)Ws;
        #pragma unroll
        for (int i = 0; i < 4; ++i)
            Wsv[t + i * 256] = Wv[t + i * 256];
        if (t < OUT_F) bs[t] = b[t];
    }
    // Stage x tile — coalesced global vf4 reads, padded LDS scatter.
    {
        const vf4* xv = (const vf4*)(x + (size_t)row0 * IN_F);
        const int nv = rows * (IN_F / 4);
        for (int i = t; i < nv; i += 256) {
            const int row = i >> 5;
            const int kk  = i & 31;
            *(vf4*)(xs + row * XS_LD + (kk << 2)) = xv[i];
        }
    }
    __syncthreads();

    const int cg  = t & 7;     // col group: cols 4cg..4cg+3
    const int rgg = t >> 3;    // row group: rows rgg, rgg+32
    const int c0  = cg << 2;

    vf4 acc0 = {0.f, 0.f, 0.f, 0.f};
    vf4 acc1 = {0.f, 0.f, 0.f, 0.f};

    #pragma unroll 4
    for (int k4 = 0; k4 < IN_F / 4; ++k4) {
        const vf4 xa = *(const vf4*)(xs + rgg * XS_LD + (k4 << 2));
        const vf4 xb = *(const vf4*)(xs + (rgg + 32) * XS_LD + (k4 << 2));
        const vf4 w0 = *(const vf4*)(Ws + ((k4 << 2) + 0) * OUT_F + c0);
        const vf4 w1 = *(const vf4*)(Ws + ((k4 << 2) + 1) * OUT_F + c0);
        const vf4 w2 = *(const vf4*)(Ws + ((k4 << 2) + 2) * OUT_F + c0);
        const vf4 w3 = *(const vf4*)(Ws + ((k4 << 2) + 3) * OUT_F + c0);

        acc0 += xa.x * w0;  acc0 += xa.y * w1;
        acc0 += xa.z * w2;  acc0 += xa.w * w3;
        acc1 += xb.x * w0;  acc1 += xb.y * w1;
        acc1 += xb.z * w2;  acc1 += xb.w * w3;
    }

    const vf4 bb = *(const vf4*)(bs + c0);

    if (rgg < rows)
        *(vf4*)(z + (size_t)(row0 + rgg) * OUT_F + c0) = acc0 + bb;
    if (rgg + 32 < rows)
        *(vf4*)(z + (size_t)(row0 + rgg + 32) * OUT_F + c0) = acc1 + bb;
}

// ---------------------------------------------------------------------------
// Kernel 2: out[e][:] = vals[e] * (z[rows[e]][:] + z[cols[e]][:])
// Geometry IDENTICAL to round-0 (one thread per (edge, quad); no grid-stride
// — the r1 12-deep dependent chain was the regression).
// SINGLE CHANGE vs round-0: streaming cache policy. out (205 MB write-once),
// erows/ecols/evals (19 MB read-once) use nontemporal accesses so they don't
// flush z (12.8 MB, randomly gathered 410 MB worth) out of the 4 MB per-XCD
// L2s. z gathers stay on the normal cached path.
// ---------------------------------------------------------------------------
__global__ __launch_bounds__(256) void edge_kernel(
    const int* __restrict__ erows, const int* __restrict__ ecols,
    const float* __restrict__ evals, const float* __restrict__ z,
    float* __restrict__ out, int n_edges)
{
    const size_t g = (size_t)blockIdx.x * 256 + threadIdx.x;
    const size_t e = g >> 3;
    if (e >= (size_t)n_edges) return;
    const int joff = (int)(g & 7) << 2;   // 0,4,8,...,28

    const int   r = __builtin_nontemporal_load(erows + e);
    const int   c = __builtin_nontemporal_load(ecols + e);
    const float w = __builtin_nontemporal_load(evals + e);

    const vf4 zr = *(const vf4*)(z + (size_t)r * OUT_F + joff);
    const vf4 zc = *(const vf4*)(z + (size_t)c * OUT_F + joff);

    vf4 o;
    o.x = w * (zr.x + zc.x);
    o.y = w * (zr.y + zc.y);
    o.z = w * (zr.z + zc.z);
    o.w = w * (zr.w + zc.w);

    __builtin_nontemporal_store(o, (vf4*)(out + e * OUT_F + joff));
}

extern "C" void kernel_launch(void* const* d_in, const int* in_sizes, int n_in,
                              void* d_out, int out_size, void* d_ws, size_t ws_size,
                              hipStream_t stream)
{
    const float* x  = (const float*)d_in[0];   // (100000, 128)
    const float* W  = (const float*)d_in[1];   // (128, 32)
    const float* b  = (const float*)d_in[2];   // (32,)
    const int* erow = (const int*)d_in[3];     // (E,) int32
    const int* ecol = (const int*)d_in[4];     // (E,) int32
    const float* ev = (const float*)d_in[5];   // (E,)

    const int n_nodes = in_sizes[0] / IN_F;
    const int n_edges = in_sizes[3];

    float* z   = (float*)d_ws;                 // n_nodes*32*4 = 12.8 MB scratch
    float* out = (float*)d_out;                // (E, 32)

    const int gemm_blocks = (n_nodes + 63) / 64;
    zgemm_kernel<<<gemm_blocks, 256, 0, stream>>>(x, W, b, z, n_nodes);

    const size_t total_thr = (size_t)n_edges * 8;
    const int edge_blocks = (int)((total_thr + 255) / 256);
    edge_kernel<<<edge_blocks, 256, 0, stream>>>(erow, ecol, ev, z, out, n_edges);
}

// Round 5
// 297.905 us; speedup vs baseline: 1.1449x; 1.0394x over previous
//
#include <hip/hip_runtime.h>

#define IN_F 128
#define OUT_F 32
#define XS_LD 132   // 128 + 4 pad: vf4-aligned (132*4 = 33*16) and 8 wave-rows
                    // tile all 32 banks exactly once -> conflict-free b128.

typedef float vf4 __attribute__((ext_vector_type(4)));
typedef _Float16 hf4 __attribute__((ext_vector_type(4)));
typedef _Float16 hf8 __attribute__((ext_vector_type(8)));

// ---------------------------------------------------------------------------
// Kernel 1: z = x @ W + b   (100000 x 128) * (128 x 32)
// Same as round 3/4 (conflict-free broadcast LDS reads, VALU-bound loop).
// ONLY change: epilogue packs z to fp16 (z table 12.8 -> 6.4 MB so the edge
// kernel's random gathers see 2x the L2-resident fraction at half the bytes;
// |z|max ~ 5.2 so fp16 adds <= ~2.6e-3 abs error/elem, budget is 0.03125).
// ---------------------------------------------------------------------------
__global__ __launch_bounds__(256) void zgemm_kernel(
    const float* __restrict__ x, const float* __restrict__ W,
    const float* __restrict__ b, _Float16* __restrict__ zh, int n_nodes)
{
    __shared__ float xs[64 * XS_LD];     // 33.8 KB (padded)
    __shared__ float Ws[IN_F * OUT_F];   // 16 KB, row-major as in global
    __shared__ float bs[OUT_F];

    const int t = threadIdx.x;
    const int row0 = blockIdx.x * 64;
    const int rows = min(64, n_nodes - row0);

    // Stage W (1024 vf4, 4 per thread) — coalesced.
    {
        const vf4* Wv = (const vf4*)W;
        vf4* Wsv = (vf4*)Ws;
        #pragma unroll
        for (int i = 0; i < 4; ++i)
            Wsv[t + i * 256] = Wv[t + i * 256];
        if (t < OUT_F) bs[t] = b[t];
    }
    // Stage x tile — coalesced global vf4 reads, padded LDS scatter.
    {
        const vf4* xv = (const vf4*)(x + (size_t)row0 * IN_F);
        const int nv = rows * (IN_F / 4);
        for (int i = t; i < nv; i += 256) {
            const int row = i >> 5;
            const int kk  = i & 31;
            *(vf4*)(xs + row * XS_LD + (kk << 2)) = xv[i];
        }
    }
    __syncthreads();

    const int cg  = t & 7;     // col group: cols 4cg..4cg+3
    const int rgg = t >> 3;    // row group: rows rgg, rgg+32
    const int c0  = cg << 2;

    vf4 acc0 = {0.f, 0.f, 0.f, 0.f};
    vf4 acc1 = {0.f, 0.f, 0.f, 0.f};

    #pragma unroll 4
    for (int k4 = 0; k4 < IN_F / 4; ++k4) {
        const vf4 xa = *(const vf4*)(xs + rgg * XS_LD + (k4 << 2));
        const vf4 xb = *(const vf4*)(xs + (rgg + 32) * XS_LD + (k4 << 2));
        const vf4 w0 = *(const vf4*)(Ws + ((k4 << 2) + 0) * OUT_F + c0);
        const vf4 w1 = *(const vf4*)(Ws + ((k4 << 2) + 1) * OUT_F + c0);
        const vf4 w2 = *(const vf4*)(Ws + ((k4 << 2) + 2) * OUT_F + c0);
        const vf4 w3 = *(const vf4*)(Ws + ((k4 << 2) + 3) * OUT_F + c0);

        acc0 += xa.x * w0;  acc0 += xa.y * w1;
        acc0 += xa.z * w2;  acc0 += xa.w * w3;
        acc1 += xb.x * w0;  acc1 += xb.y * w1;
        acc1 += xb.z * w2;  acc1 += xb.w * w3;
    }

    const vf4 bb = *(const vf4*)(bs + c0);
    const vf4 r0 = acc0 + bb;
    const vf4 r1 = acc1 + bb;

    if (rgg < rows) {
        hf4 h = { (_Float16)r0.x, (_Float16)r0.y, (_Float16)r0.z, (_Float16)r0.w };
        *(hf4*)(zh + (size_t)(row0 + rgg) * OUT_F + c0) = h;
    }
    if (rgg + 32 < rows) {
        hf4 h = { (_Float16)r1.x, (_Float16)r1.y, (_Float16)r1.z, (_Float16)r1.w };
        *(hf4*)(zh + (size_t)(row0 + rgg + 32) * OUT_F + c0) = h;
    }
}

// ---------------------------------------------------------------------------
// Kernel 2: out[e][:] = vals[e] * (z[rows[e]][:] + z[cols[e]][:]), z in fp16.
// 4 lanes/edge (was 8): each lane loads 16 B from each z row (8 halves) and
// writes 32 B of out -> per-edge MLP unchanged at HALF the threads = 2x the
// outstanding loads per thread for latency hiding. Wave = 16 edges, writes
// 2 KB contiguous. Gather volume halves (205 MB) against a 6.4 MB z table.
// NT policy from round 4 kept: streams bypass L2, z stays cached.
// ---------------------------------------------------------------------------
__global__ __launch_bounds__(256) void edge_kernel(
    const int* __restrict__ erows, const int* __restrict__ ecols,
    const float* __restrict__ evals, const _Float16* __restrict__ zh,
    float* __restrict__ out, int n_edges)
{
    const size_t g = (size_t)blockIdx.x * 256 + threadIdx.x;
    const size_t e = g >> 2;
    if (e >= (size_t)n_edges) return;
    const int coff = (int)(g & 3) << 3;   // 0, 8, 16, 24

    const int   r = __builtin_nontemporal_load(erows + e);
    const int   c = __builtin_nontemporal_load(ecols + e);
    const float w = __builtin_nontemporal_load(evals + e);

    const hf8 zr = *(const hf8*)(zh + (size_t)r * OUT_F + coff);
    const hf8 zc = *(const hf8*)(zh + (size_t)c * OUT_F + coff);

    vf4 o0, o1;
    o0.x = w * ((float)zr[0] + (float)zc[0]);
    o0.y = w * ((float)zr[1] + (float)zc[1]);
    o0.z = w * ((float)zr[2] + (float)zc[2]);
    o0.w = w * ((float)zr[3] + (float)zc[3]);
    o1.x = w * ((float)zr[4] + (float)zc[4]);
    o1.y = w * ((float)zr[5] + (float)zc[5]);
    o1.z = w * ((float)zr[6] + (float)zc[6]);
    o1.w = w * ((float)zr[7] + (float)zc[7]);

    float* op = out + e * OUT_F + coff;
    __builtin_nontemporal_store(o0, (vf4*)op);
    __builtin_nontemporal_store(o1, (vf4*)(op + 4));
}

extern "C" void kernel_launch(void* const* d_in, const int* in_sizes, int n_in,
                              void* d_out, int out_size, void* d_ws, size_t ws_size,
                              hipStream_t stream)
{
    const float* x  = (const float*)d_in[0];   // (100000, 128)
    const float* W  = (const float*)d_in[1];   // (128, 32)
    const float* b  = (const float*)d_in[2];   // (32,)
    const int* erow = (const int*)d_in[3];     // (E,) int32
    const int* ecol = (const int*)d_in[4];     // (E,) int32
    const float* ev = (const float*)d_in[5];   // (E,)

    const int n_nodes = in_sizes[0] / IN_F;
    const int n_edges = in_sizes[3];

    _Float16* zh = (_Float16*)d_ws;            // n_nodes*32*2 = 6.4 MB scratch
    float* out = (float*)d_out;                // (E, 32)

    const int gemm_blocks = (n_nodes + 63) / 64;
    zgemm_kernel<<<gemm_blocks, 256, 0, stream>>>(x, W, b, zh, n_nodes);

    const size_t total_thr = (size_t)n_edges * 4;
    const int edge_blocks = (int)((total_thr + 255) / 256);
    edge_kernel<<<edge_blocks, 256, 0, stream>>>(erow, ecol, ev, zh, out, n_edges);
}